// Round 15
// baseline (140.165 us; speedup 1.0000x reference)
//
#include <hip/hip_runtime.h>
#include <math.h>

// Problem constants (B, S, E, WIN) = (8, 2048, 512, 11)
#define B_    8
#define S_    2048
#define E_    512
#define WIN_  11
#define WW    5              // WIN/2
#define F4C   1408           // float4 per W row (5632/4)
#define E4C   128            // float4 per x row (512/4)
#define PSTR  (B_ * WIN_)    // 88 gate logits per s

typedef __attribute__((ext_vector_type(4))) float f32x4;

// ---- DPP wave-sum: 6 VALU ops, zero DS-pipe traffic. Full sum -> lane 63.
template <int CTRL, int RMASK>
__device__ __forceinline__ float dpp_add(float v) {
    int sh = __builtin_amdgcn_update_dpp(0, __float_as_int(v),
                                         CTRL, RMASK, 0xF, true);
    return v + __int_as_float(sh);
}
__device__ __forceinline__ float wave_sum63(float v) {
    v = dpp_add<0x111, 0xF>(v);   // row_shr:1
    v = dpp_add<0x112, 0xF>(v);   // row_shr:2
    v = dpp_add<0x114, 0xF>(v);   // row_shr:4
    v = dpp_add<0x118, 0xF>(v);   // row_shr:8
    v = dpp_add<0x142, 0xA>(v);   // row_bcast:15
    v = dpp_add<0x143, 0xC>(v);   // row_bcast:31 -> lane 63 = full sum
    return v;
}

__device__ __forceinline__ float tanh_fast(float v) {
    const float e = __expf(v + v);
    return 1.f - 2.f / (e + 1.f);
}

// ---------------------------------------------------------------------------
// R15 = R14 (NT W staging, fused, DPP reduce) + two changes:
//  1. x is NOT staged in LDS — read as VGPR float4 loads in the compute
//     phase. Post-NT, x is L2-resident; the LDS round-trip was costing
//     16/22 of the per-chunk ds_read_b128s (DS pipe ~264 cyc/wave/chunk)
//     plus 16 KB LDS. Now: LDS 38.9 -> 22.9 KB => 5+ blocks/CU (+25% TLP
//     through the stage-drain), DS reads 22 -> 6 per thread/chunk, and
//     each drain waits on 6 gl_lds instead of 10.
//  2. out stores are non-temporal (pure streaming write; stop it evicting
//     x from L2/L3).
// Everything else identical to R14.
// ---------------------------------------------------------------------------
__global__ __launch_bounds__(256)
void win_attn_fused(const float* __restrict__ x,
                    const float* __restrict__ W,
                    const float* __restrict__ bias,
                    float* __restrict__ out)
{
    const int bid  = blockIdx.x;
    const int s    = (bid & 7) * (S_ / 8) + (bid >> 3);   // bijective XCD swizzle
    const int tid  = threadIdx.x;
    const int wid  = tid >> 6;      // wave 0..3
    const int lane = tid & 63;

    const float4* __restrict__ X4 = reinterpret_cast<const float4*>(x);
    const float4* __restrict__ Ws = reinterpret_cast<const float4*>(W)
                                    + (size_t)s * (WIN_ * F4C);

    __shared__ float4 Wbuf[WIN_ * E4C];   // 22.5 KB: [w][e4] for current wp
    __shared__ float gates[PSTR];

    const int w0   = wid * 3;                  // first w-row of this wave
    const int wcnt = (wid == 3) ? 2 : 3;       // wave 3 owns rows 9,10

    float acc[B_][3];
    #pragma unroll
    for (int b = 0; b < B_; ++b)
        #pragma unroll
        for (int j = 0; j < 3; ++j) acc[b][j] = 0.f;

    const int wpLo = (s >= WW) ? 0 : (WW - s);
    const int wpHi = (WIN_ < S_ + WW - s) ? WIN_ : (S_ + WW - s);

    #pragma unroll 1
    for (int wp = wpLo; wp < wpHi; ++wp) {
        const int row = s - WW + wp;      // always valid in [wpLo, wpHi)

        // ---- stage W chunk (1408 f4, NT) into LDS ----
        #pragma unroll
        for (int j = 0; j < 6; ++j) {
            const int m = j * 256 + tid;          // [0,1536)
            if (j < 5 || wid < 2) {               // wave-uniform guard (m<1408)
                const int w  = m >> 7;
                const int e4 = m & 127;
                const float4* src = Ws + (size_t)w * F4C + wp * E4C + e4;
                __builtin_amdgcn_global_load_lds(
                    (const __attribute__((address_space(1))) void*)src,
                    (__attribute__((address_space(3))) void*)&Wbuf[m],
                    16, 0, 2 /* NT: stream W, don't evict x from L2/L3 */);
            }
        }
        __syncthreads();   // staging complete (vmcnt drain)

        // ---- compute: W from LDS (6 ds_reads), x straight from L2 ----
        float4 wv[3][2];
        #pragma unroll
        for (int j = 0; j < 3; ++j)
            if (j < wcnt) {
                wv[j][0] = Wbuf[(w0 + j) * E4C + lane];
                wv[j][1] = Wbuf[(w0 + j) * E4C + lane + 64];
            }

        #pragma unroll
        for (int half = 0; half < 2; ++half) {
            float4 xv[4][2];
            #pragma unroll
            for (int bb = 0; bb < 4; ++bb) {
                const int b = half * 4 + bb;
                const float4* xr = X4 + ((size_t)b * S_ + row) * E4C;
                xv[bb][0] = xr[lane];
                xv[bb][1] = xr[lane + 64];
            }
            #pragma unroll
            for (int bb = 0; bb < 4; ++bb) {
                const int b = half * 4 + bb;
                #pragma unroll
                for (int j = 0; j < 3; ++j)
                    if (j < wcnt) {
                        float a = acc[b][j];
                        a = fmaf(xv[bb][0].x, wv[j][0].x, a);
                        a = fmaf(xv[bb][0].y, wv[j][0].y, a);
                        a = fmaf(xv[bb][0].z, wv[j][0].z, a);
                        a = fmaf(xv[bb][0].w, wv[j][0].w, a);
                        a = fmaf(xv[bb][1].x, wv[j][1].x, a);
                        a = fmaf(xv[bb][1].y, wv[j][1].y, a);
                        a = fmaf(xv[bb][1].z, wv[j][1].z, a);
                        a = fmaf(xv[bb][1].w, wv[j][1].w, a);
                        acc[b][j] = a;
                    }
            }
        }
        __syncthreads();   // WAR: all Wbuf reads done before next chunk stages
    }

    // ---- DPP reduce (VALU only) -> gate logits -> sigmoid ----
    #pragma unroll
    for (int b = 0; b < B_; ++b)
        #pragma unroll
        for (int j = 0; j < 3; ++j)
            if (j < wcnt) acc[b][j] = wave_sum63(acc[b][j]);

    if (lane == 63) {
        #pragma unroll
        for (int b = 0; b < B_; ++b)
            #pragma unroll
            for (int j = 0; j < 3; ++j)
                if (j < wcnt) gates[b * WIN_ + w0 + j] = acc[b][j];
    }
    __syncthreads();

    if (tid < PSTR) {
        const int w = tid % WIN_;
        const float v = gates[tid] + bias[s * WIN_ + w];
        gates[tid] = 1.f / (1.f + __expf(-v));
    }
    __syncthreads();

    // ---- score + tanh; x L2-hot, out streamed with NT stores ----
    f32x4* __restrict__ OUT4 = reinterpret_cast<f32x4*>(out);
    #pragma unroll
    for (int it = 0; it < 4; ++it) {
        const int i  = tid + (it << 8);   // 0..1023 -> (b, e4)
        const int b  = i >> 7;
        const int e4 = i & 127;
        float4 sc = make_float4(0.f, 0.f, 0.f, 0.f);
        #pragma unroll
        for (int w = 0; w < WIN_; ++w) {
            const int r = s - WW + w;
            if (r >= 0 && r < S_) {
                const float g   = gates[b * WIN_ + w];
                const float4 xv = X4[((size_t)b * S_ + r) * E4C + e4];
                sc.x = fmaf(g, xv.x, sc.x);
                sc.y = fmaf(g, xv.y, sc.y);
                sc.z = fmaf(g, xv.z, sc.z);
                sc.w = fmaf(g, xv.w, sc.w);
            }
        }
        f32x4 o;
        o.x = tanh_fast(sc.x);
        o.y = tanh_fast(sc.y);
        o.z = tanh_fast(sc.z);
        o.w = tanh_fast(sc.w);
        __builtin_nontemporal_store(o, &OUT4[((size_t)b * S_ + s) * E4C + e4]);
    }
}

extern "C" void kernel_launch(void* const* d_in, const int* in_sizes, int n_in,
                              void* d_out, int out_size, void* d_ws, size_t ws_size,
                              hipStream_t stream)
{
    const float* x    = (const float*)d_in[0];
    const float* W    = (const float*)d_in[1];
    const float* bias = (const float*)d_in[2];
    float* out        = (float*)d_out;

    win_attn_fused<<<dim3(S_), dim3(256), 0, stream>>>(x, W, bias, out);
}

// Round 16
// 129.736 us; speedup vs baseline: 1.0804x; 1.0804x over previous
//
#include <hip/hip_runtime.h>
#include <math.h>

// Problem constants (B, S, E, WIN) = (8, 2048, 512, 11)
#define B_    8
#define S_    2048
#define E_    512
#define WIN_  11
#define WW    5              // WIN/2
#define F4C   1408           // float4 per W row (5632/4)
#define E4C   128            // float4 per x row (512/4)
#define PSTR  (B_ * WIN_)    // 88 gate logits per s

// ---- DPP wave-sum: 6 VALU ops, zero DS-pipe traffic. Full sum -> lane 63.
template <int CTRL, int RMASK>
__device__ __forceinline__ float dpp_add(float v) {
    int sh = __builtin_amdgcn_update_dpp(0, __float_as_int(v),
                                         CTRL, RMASK, 0xF, true);
    return v + __int_as_float(sh);
}
__device__ __forceinline__ float wave_sum63(float v) {
    v = dpp_add<0x111, 0xF>(v);   // row_shr:1
    v = dpp_add<0x112, 0xF>(v);   // row_shr:2
    v = dpp_add<0x114, 0xF>(v);   // row_shr:4
    v = dpp_add<0x118, 0xF>(v);   // row_shr:8
    v = dpp_add<0x142, 0xA>(v);   // row_bcast:15
    v = dpp_add<0x143, 0xC>(v);   // row_bcast:31 -> lane 63 = full sum
    return v;
}

__device__ __forceinline__ float tanh_fast(float v) {
    const float e = __expf(v + v);
    return 1.f - 2.f / (e + 1.f);
}

// ---------------------------------------------------------------------------
// R16 = R14 (best: NT-W gl_lds staging, x staged in LDS, DPP reduce, fused
// epilogue) with ONE variable changed: chunk = (wp, e-half) instead of full-e.
//   LDS/buffer: W 11 KB + x 8 KB + gates = 19.4 KB  (was 38.9)
//   VGPR: xv 8x1 f4 (32) + wv 3x1 (12) + acc 24     (was ~110) -> ~90
//   => 5-6 blocks/CU (was 4): more independent stage->drain->compute streams
//   in flight per CU; their drains interleave -> HBM issue duty ~full.
// 22 chunks x [stage 5 gl_lds -> __syncthreads -> 11 ds_read + 44 FMA ->
// __syncthreads]. Same total bytes as R14.
// ---------------------------------------------------------------------------
__global__ __launch_bounds__(256)
void win_attn_fused(const float* __restrict__ x,
                    const float* __restrict__ W,
                    const float* __restrict__ bias,
                    float* __restrict__ out)
{
    const int bid  = blockIdx.x;
    const int s    = (bid & 7) * (S_ / 8) + (bid >> 3);   // bijective XCD swizzle
    const int tid  = threadIdx.x;
    const int wid  = tid >> 6;      // wave 0..3
    const int lane = tid & 63;

    const float4* __restrict__ X4 = reinterpret_cast<const float4*>(x);
    const float4* __restrict__ Ws = reinterpret_cast<const float4*>(W)
                                    + (size_t)s * (WIN_ * F4C);

    __shared__ float4 Wb[WIN_ * 64];   // 11 KB: [w][64] current (wp, half)
    __shared__ float4 xb[B_ * 64];     // 8 KB:  [b][64] current (row, half)
    __shared__ float gates[PSTR];

    const int w0   = wid * 3;                  // first w-row of this wave
    const int wcnt = (wid == 3) ? 2 : 3;       // wave 3 owns rows 9,10

    float acc[B_][3];
    #pragma unroll
    for (int b = 0; b < B_; ++b)
        #pragma unroll
        for (int j = 0; j < 3; ++j) acc[b][j] = 0.f;

    const int wpLo = (s >= WW) ? 0 : (WW - s);
    const int wpHi = (WIN_ < S_ + WW - s) ? WIN_ : (S_ + WW - s);

    #pragma unroll 1
    for (int c = 2 * wpLo; c < 2 * wpHi; ++c) {
        const int wp  = c >> 1;
        const int h   = c & 1;
        const int row = s - WW + wp;          // valid by construction

        // ---- stage W half-chunk (704 f4, NT) + x half-row (512 f4) ----
        #pragma unroll
        for (int j = 0; j < 3; ++j) {
            const int m = j * 256 + tid;
            if (j < 2 || tid < 192) {          // wave-uniform (m < 704)
                const int w  = m >> 6;
                const int el = m & 63;
                const float4* src = Ws + (size_t)w * F4C + wp * E4C + h * 64 + el;
                __builtin_amdgcn_global_load_lds(
                    (const __attribute__((address_space(1))) void*)src,
                    (__attribute__((address_space(3))) void*)&Wb[m],
                    16, 0, 2 /* NT: one-shot W stream, don't evict x */);
            }
        }
        #pragma unroll
        for (int j = 0; j < 2; ++j) {
            const int n  = j * 256 + tid;      // [0,512)
            const int b  = n >> 6;
            const int el = n & 63;
            const float4* src = X4 + ((size_t)b * S_ + row) * E4C + h * 64 + el;
            __builtin_amdgcn_global_load_lds(
                (const __attribute__((address_space(1))) void*)src,
                (__attribute__((address_space(3))) void*)&xb[n],
                16, 0, 0);
        }
        __syncthreads();   // staging complete (vmcnt drain)

        // ---- compute half-chunk: 11 ds_read_b128 + 44 FMA4 ----
        float4 wv[3];
        #pragma unroll
        for (int j = 0; j < 3; ++j)
            if (j < wcnt) wv[j] = Wb[(w0 + j) * 64 + lane];

        float4 xv[B_];
        #pragma unroll
        for (int b = 0; b < B_; ++b) xv[b] = xb[b * 64 + lane];

        #pragma unroll
        for (int b = 0; b < B_; ++b)
            #pragma unroll
            for (int j = 0; j < 3; ++j)
                if (j < wcnt) {
                    float a = acc[b][j];
                    a = fmaf(xv[b].x, wv[j].x, a);
                    a = fmaf(xv[b].y, wv[j].y, a);
                    a = fmaf(xv[b].z, wv[j].z, a);
                    a = fmaf(xv[b].w, wv[j].w, a);
                    acc[b][j] = a;
                }

        __syncthreads();   // WAR: reads done before next chunk stages
    }

    // ---- DPP reduce (VALU only) -> gate logits -> sigmoid ----
    #pragma unroll
    for (int b = 0; b < B_; ++b)
        #pragma unroll
        for (int j = 0; j < 3; ++j)
            if (j < wcnt) acc[b][j] = wave_sum63(acc[b][j]);

    if (lane == 63) {
        #pragma unroll
        for (int b = 0; b < B_; ++b)
            #pragma unroll
            for (int j = 0; j < 3; ++j)
                if (j < wcnt) gates[b * WIN_ + w0 + j] = acc[b][j];
    }
    __syncthreads();

    if (tid < PSTR) {
        const int w = tid % WIN_;
        const float v = gates[tid] + bias[s * WIN_ + w];
        gates[tid] = 1.f / (1.f + __expf(-v));
    }
    __syncthreads();

    // ---- score + tanh (identical to R14) ----
    float4* __restrict__ OUT4 = reinterpret_cast<float4*>(out);
    #pragma unroll
    for (int it = 0; it < 4; ++it) {
        const int i  = tid + (it << 8);   // 0..1023 -> (b, e4)
        const int b  = i >> 7;
        const int e4 = i & 127;
        float4 sc = make_float4(0.f, 0.f, 0.f, 0.f);
        #pragma unroll
        for (int w = 0; w < WIN_; ++w) {
            const int r = s - WW + w;
            if (r >= 0 && r < S_) {
                const float g   = gates[b * WIN_ + w];
                const float4 xv = X4[((size_t)b * S_ + r) * E4C + e4];
                sc.x = fmaf(g, xv.x, sc.x);
                sc.y = fmaf(g, xv.y, sc.y);
                sc.z = fmaf(g, xv.z, sc.z);
                sc.w = fmaf(g, xv.w, sc.w);
            }
        }
        float4 o;
        o.x = tanh_fast(sc.x);
        o.y = tanh_fast(sc.y);
        o.z = tanh_fast(sc.z);
        o.w = tanh_fast(sc.w);
        OUT4[((size_t)b * S_ + s) * E4C + e4] = o;
    }
}

extern "C" void kernel_launch(void* const* d_in, const int* in_sizes, int n_in,
                              void* d_out, int out_size, void* d_ws, size_t ws_size,
                              hipStream_t stream)
{
    const float* x    = (const float*)d_in[0];
    const float* W    = (const float*)d_in[1];
    const float* bias = (const float*)d_in[2];
    float* out        = (float*)d_out;

    win_attn_fused<<<dim3(S_), dim3(256), 0, stream>>>(x, W, bias, out);
}